// Round 2
// baseline (62.709 us; speedup 1.0000x reference)
//
#include <hip/hip_runtime.h>

// OHEM loss via per-row count-only histogram select.
// 64 rows = 32 samples x 2 channels (0: region/char, 1: affinity).
// Negatives (label < 0.1): u32 count histogram over loss p^2 in [0,1), 2048 bins.
//   top-k sum reconstructed from bin midpoints (bias ~2e-8 per elem << 3.95e-2 budget).
// Positives: exact fixed-point sum + count in registers, one packed u64 atomic/wave.

#define NB 2048
#define ROWSTRIDE 2080          // u32 stride per row (2048 bins + pad)
#define NPIX 262144             // 512*512
#define C_CHUNKS 16
#define BLK 512
#define CHUNK (NPIX / C_CHUNKS) // 16384 elems per block
#define SCALE 1048576.0f        // 2^20 fixed point for positive sums
#define INV_SCALE (1.0 / 1048576.0)

__global__ __launch_bounds__(BLK)
void ohem_hist_kernel(const float* __restrict__ pred,
                      const float* __restrict__ region,
                      const float* __restrict__ affinity,
                      unsigned int* __restrict__ g_hist,
                      unsigned long long* __restrict__ g_pos)
{
    __shared__ unsigned int h[NB];
    const int row   = blockIdx.x / C_CHUNKS;   // 0..63
    const int chunk = blockIdx.x % C_CHUNKS;
    const int b = row & 31;
    const int c = row >> 5;                    // 0: region, 1: affinity
    const float4* p4 = (const float4*)(pred + (size_t)(b * 2 + c) * NPIX
                                            + (size_t)chunk * CHUNK);
    const float4* s4 = (const float4*)((c == 0 ? region : affinity)
                                       + (size_t)b * NPIX + (size_t)chunk * CHUNK);

    for (int i = threadIdx.x; i < NB; i += BLK) h[i] = 0;
    __syncthreads();

    unsigned int poscnt = 0, possum = 0;       // per-thread exact positive accum
    #pragma unroll
    for (int it = 0; it < CHUNK / (BLK * 4); ++it) {   // 8 iterations
        float4 pv = p4[it * BLK + threadIdx.x];
        float4 sv = s4[it * BLK + threadIdx.x];
        float pp[4]  = {pv.x, pv.y, pv.z, pv.w};
        float ss[4]  = {sv.x, sv.y, sv.z, sv.w};
        #pragma unroll
        for (int j = 0; j < 4; ++j) {
            float d = pp[j] - ss[j];
            float x = d * d;                   // pre_loss in [0,1)
            if (ss[j] >= 0.1f) {
                poscnt += 1;
                possum += (unsigned int)(x * SCALE + 0.5f);  // <= 2^20 per val
            } else {
                int bin = (int)(x * (float)NB);
                if (bin > NB - 1) bin = NB - 1;
                atomicAdd(&h[bin], 1u);        // u32 LDS atomic, count only
            }
        }
    }

    // Per-wave reduce of positives: pack (cnt << 40) | fixedsum.
    // Per-lane fixedsum <= 32*2^20 = 2^25; wave sum <= 2^31 < 2^40. cnt wave sum <= 2048.
    unsigned long long pp64 = ((unsigned long long)poscnt << 40)
                            | (unsigned long long)possum;
    #pragma unroll
    for (int off = 32; off > 0; off >>= 1) pp64 += __shfl_down(pp64, off);
    if ((threadIdx.x & 63) == 0 && pp64) atomicAdd(&g_pos[row], pp64);

    __syncthreads();
    unsigned int* gh = g_hist + (size_t)row * ROWSTRIDE;
    for (int i = threadIdx.x; i < NB; i += BLK) {
        unsigned int v = h[i];
        if (v) atomicAdd(&gh[i], v);
    }
}

__global__ __launch_bounds__(64)
void ohem_select_kernel(const unsigned int* __restrict__ g_hist,
                        const unsigned long long* __restrict__ g_pos,
                        float* __restrict__ row_result)
{
    const int row = blockIdx.x;
    const unsigned int* gh = g_hist + (size_t)row * ROWSTRIDE;
    const int t = threadIdx.x;   // single wave of 64

    // Lane t owns 32 consecutive bins counted FROM THE TOP.
    unsigned long long c_t = 0;
    double w_t = 0.0;            // sum of cnt * (bin + 0.5)
    for (int j = 0; j < 32; ++j) {
        int bin = NB - 1 - (t * 32 + j);
        unsigned int v = gh[bin];
        c_t += v;
        w_t += (double)v * ((double)bin + 0.5);
    }
    // Inclusive scan across the wave.
    unsigned long long ic = c_t; double iw = w_t;
    for (int off = 1; off < 64; off <<= 1) {
        unsigned long long uc = __shfl_up(ic, off);
        double             uw = __shfl_up(iw, off);
        if (t >= off) { ic += uc; iw += uw; }
    }
    unsigned long long pre_c = ic - c_t;      // exclusive prefix (from top)
    double pre_w = iw - w_t;

    unsigned long long pospack = g_pos[row];
    unsigned long long pc = pospack >> 40;
    double psum = (double)(pospack & ((1ULL << 40) - 1)) * INV_SCALE;
    long long negc = (long long)NPIX - (long long)pc;
    long long k;
    if (pc > 0) { k = 3LL * (long long)pc; if (k > negc) k = negc; }
    else        { k = 500; }                  // top-500-mean fallback

    if (pc > 0 && k == 0) {                   // all pixels positive: nega = -1
        if (t == 0) row_result[row] = (float)(psum / (double)pc - 1.0);
        return;
    }

    // Exactly one lane contains the k-th value crossing.
    if ((long long)pre_c < k && k <= (long long)(pre_c + c_t)) {
        unsigned long long cum = pre_c;
        double cw = pre_w;
        double nega = 0.0;
        for (int j = 0; j < 32; ++j) {
            int bin = NB - 1 - (t * 32 + j);
            unsigned int v = gh[bin];
            if ((long long)(cum + v) >= k) {
                unsigned long long need = (unsigned long long)k - cum;
                nega = (cw + (double)need * ((double)bin + 0.5))
                       / (double)NB / (double)k;
                break;
            }
            cum += v;
            cw  += (double)v * ((double)bin + 0.5);
        }
        double posi = (pc > 0) ? psum / (double)pc : 0.0;
        row_result[row] = (float)(posi + nega);
    }
}

__global__ void final_reduce_kernel(const float* __restrict__ row_result,
                                    float* __restrict__ out)
{
    float v = row_result[threadIdx.x];   // 64 lanes = 64 rows
    #pragma unroll
    for (int off = 32; off > 0; off >>= 1) v += __shfl_down(v, off);
    if (threadIdx.x == 0) out[0] = v * (1.0f / 32.0f);
}

extern "C" void kernel_launch(void* const* d_in, const int* in_sizes, int n_in,
                              void* d_out, int out_size, void* d_ws, size_t ws_size,
                              hipStream_t stream)
{
    const float* pred     = (const float*)d_in[0];
    const float* region   = (const float*)d_in[1];
    const float* affinity = (const float*)d_in[2];
    float* out = (float*)d_out;

    unsigned int* g_hist = (unsigned int*)d_ws;
    const size_t hist_bytes = (size_t)64 * ROWSTRIDE * sizeof(unsigned int);
    unsigned long long* g_pos = (unsigned long long*)((char*)d_ws + hist_bytes);
    float* row_result = (float*)((char*)d_ws + hist_bytes + 64 * sizeof(unsigned long long));

    hipMemsetAsync(d_ws, 0,
                   hist_bytes + 64 * sizeof(unsigned long long) + 64 * sizeof(float),
                   stream);
    ohem_hist_kernel<<<64 * C_CHUNKS, BLK, 0, stream>>>(pred, region, affinity,
                                                        g_hist, g_pos);
    ohem_select_kernel<<<64, 64, 0, stream>>>(g_hist, g_pos, row_result);
    final_reduce_kernel<<<1, 64, 0, stream>>>(row_result, out);
}

// Round 3
// 61.937 us; speedup vs baseline: 1.0125x; 1.0125x over previous
//
#include <hip/hip_runtime.h>

// OHEM loss via per-row count-only histogram select, binned on |d|.
// 64 rows = 32 samples x 2 channels (0: region/char, 1: affinity).
// Negatives (label < 0.1): u32 count histogram over |pred-label| in [0,1),
//   NB bins. |d| is ~uniform for this data -> near-zero same-address LDS
//   atomic contention (binning on d^2 piled 2.2% of pixels into bin 0).
//   top-k by d^2 == top-k by |d| (monotone); sum rebuilt from midpoint^2
//   (per-elem error <= 1/NB << 3.95e-2 threshold).
// Positives: exact fixed-point sum + count in registers, one packed u64
//   global atomic per wave.

#define NB 1024
#define BPL (NB / 64)           // bins per lane in select kernel
#define ROWSTRIDE 1056          // u32 stride per row (1024 bins + pad)
#define NPIX 262144             // 512*512
#define C_CHUNKS 8
#define BLK 1024
#define CHUNK (NPIX / C_CHUNKS) // 32768 elems per block
#define ITERS (CHUNK / (BLK * 4))  // 8
#define SCALE 1048576.0f        // 2^20 fixed point for positive sums
#define INV_SCALE (1.0 / 1048576.0)

__global__ __launch_bounds__(BLK)
void ohem_hist_kernel(const float* __restrict__ pred,
                      const float* __restrict__ region,
                      const float* __restrict__ affinity,
                      unsigned int* __restrict__ g_hist,
                      unsigned long long* __restrict__ g_pos)
{
    __shared__ unsigned int h[NB];
    const int row   = blockIdx.x / C_CHUNKS;   // 0..63
    const int chunk = blockIdx.x % C_CHUNKS;
    const int b = row & 31;
    const int c = row >> 5;                    // 0: region, 1: affinity
    const float4* p4 = (const float4*)(pred + (size_t)(b * 2 + c) * NPIX
                                            + (size_t)chunk * CHUNK);
    const float4* s4 = (const float4*)((c == 0 ? region : affinity)
                                       + (size_t)b * NPIX + (size_t)chunk * CHUNK);

    if (threadIdx.x < NB) h[threadIdx.x] = 0;
    __syncthreads();

    unsigned int poscnt = 0, possum = 0;       // per-thread exact positive accum

    float4 pv = p4[threadIdx.x];
    float4 sv = s4[threadIdx.x];
    #pragma unroll
    for (int it = 0; it < ITERS; ++it) {
        float4 npv, nsv;
        if (it + 1 < ITERS) {                  // prefetch next tile
            npv = p4[(it + 1) * BLK + threadIdx.x];
            nsv = s4[(it + 1) * BLK + threadIdx.x];
        }
        float pp[4] = {pv.x, pv.y, pv.z, pv.w};
        float ss[4] = {sv.x, sv.y, sv.z, sv.w};
        #pragma unroll
        for (int j = 0; j < 4; ++j) {
            float d  = pp[j] - ss[j];
            float ad = fabsf(d);
            int bin = (int)(ad * (float)NB);   // |d| < 1 always here
            if (bin > NB - 1) bin = NB - 1;
            bool pos = (ss[j] >= 0.1f);
            if (!pos) atomicAdd(&h[bin], 1u);  // near-uniform bins: ~no contention
            poscnt += pos ? 1u : 0u;
            possum += pos ? (unsigned int)(d * d * SCALE + 0.5f) : 0u;
        }
        pv = npv; sv = nsv;
    }

    // Per-wave reduce of positives: pack (cnt << 40) | fixedsum.
    // Per-lane fixedsum <= 32*2^20 = 2^25; wave sum <= 2^31 < 2^40.
    unsigned long long pp64 = ((unsigned long long)poscnt << 40)
                            | (unsigned long long)possum;
    #pragma unroll
    for (int off = 32; off > 0; off >>= 1) pp64 += __shfl_down(pp64, off);
    if ((threadIdx.x & 63) == 0 && pp64) atomicAdd(&g_pos[row], pp64);

    __syncthreads();
    unsigned int* gh = g_hist + (size_t)row * ROWSTRIDE;
    if (threadIdx.x < NB) {
        unsigned int v = h[threadIdx.x];
        if (v) atomicAdd(&gh[threadIdx.x], v);
    }
}

__global__ __launch_bounds__(64)
void ohem_select_kernel(const unsigned int* __restrict__ g_hist,
                        const unsigned long long* __restrict__ g_pos,
                        float* __restrict__ row_result)
{
    const int row = blockIdx.x;
    const unsigned int* gh = g_hist + (size_t)row * ROWSTRIDE;
    const int t = threadIdx.x;   // single wave of 64

    // Lane t owns BPL consecutive bins counted FROM THE TOP (descending |d|).
    unsigned long long c_t = 0;
    double w_t = 0.0;            // sum of cnt * midpoint^2 (= sum of d^2 values)
    for (int j = 0; j < BPL; ++j) {
        int bin = NB - 1 - (t * BPL + j);
        unsigned int v = gh[bin];
        double m = ((double)bin + 0.5) / (double)NB;
        c_t += v;
        w_t += (double)v * m * m;
    }
    // Inclusive scan across the wave.
    unsigned long long ic = c_t; double iw = w_t;
    for (int off = 1; off < 64; off <<= 1) {
        unsigned long long uc = __shfl_up(ic, off);
        double             uw = __shfl_up(iw, off);
        if (t >= off) { ic += uc; iw += uw; }
    }
    unsigned long long pre_c = ic - c_t;      // exclusive prefix (from top)
    double pre_w = iw - w_t;

    unsigned long long pospack = g_pos[row];
    unsigned long long pc = pospack >> 40;
    double psum = (double)(pospack & ((1ULL << 40) - 1)) * INV_SCALE;
    long long negc = (long long)NPIX - (long long)pc;
    long long k;
    if (pc > 0) { k = 3LL * (long long)pc; if (k > negc) k = negc; }
    else        { k = 500; }                  // top-500-mean fallback

    if (pc > 0 && k == 0) {                   // all pixels positive: nega = -1
        if (t == 0) row_result[row] = (float)(psum / (double)pc - 1.0);
        return;
    }

    // Exactly one lane contains the k-th value crossing.
    if ((long long)pre_c < k && k <= (long long)(pre_c + c_t)) {
        unsigned long long cum = pre_c;
        double cw = pre_w;
        double nega = 0.0;
        for (int j = 0; j < BPL; ++j) {
            int bin = NB - 1 - (t * BPL + j);
            unsigned int v = gh[bin];
            double m = ((double)bin + 0.5) / (double)NB;
            if ((long long)(cum + v) >= k) {
                unsigned long long need = (unsigned long long)k - cum;
                nega = (cw + (double)need * m * m) / (double)k;
                break;
            }
            cum += v;
            cw  += (double)v * m * m;
        }
        double posi = (pc > 0) ? psum / (double)pc : 0.0;
        row_result[row] = (float)(posi + nega);
    }
}

__global__ void final_reduce_kernel(const float* __restrict__ row_result,
                                    float* __restrict__ out)
{
    float v = row_result[threadIdx.x];   // 64 lanes = 64 rows
    #pragma unroll
    for (int off = 32; off > 0; off >>= 1) v += __shfl_down(v, off);
    if (threadIdx.x == 0) out[0] = v * (1.0f / 32.0f);
}

extern "C" void kernel_launch(void* const* d_in, const int* in_sizes, int n_in,
                              void* d_out, int out_size, void* d_ws, size_t ws_size,
                              hipStream_t stream)
{
    const float* pred     = (const float*)d_in[0];
    const float* region   = (const float*)d_in[1];
    const float* affinity = (const float*)d_in[2];
    float* out = (float*)d_out;

    unsigned int* g_hist = (unsigned int*)d_ws;
    const size_t hist_bytes = (size_t)64 * ROWSTRIDE * sizeof(unsigned int);
    unsigned long long* g_pos = (unsigned long long*)((char*)d_ws + hist_bytes);
    float* row_result = (float*)((char*)d_ws + hist_bytes + 64 * sizeof(unsigned long long));

    hipMemsetAsync(d_ws, 0,
                   hist_bytes + 64 * sizeof(unsigned long long) + 64 * sizeof(float),
                   stream);
    ohem_hist_kernel<<<64 * C_CHUNKS, BLK, 0, stream>>>(pred, region, affinity,
                                                        g_hist, g_pos);
    ohem_select_kernel<<<64, 64, 0, stream>>>(g_hist, g_pos, row_result);
    final_reduce_kernel<<<1, 64, 0, stream>>>(row_result, out);
}